// Round 9
// baseline (238.970 us; speedup 1.0000x reference)
//
#include <hip/hip_runtime.h>
#include <hip/hip_bf16.h>
#include <math.h>

typedef __bf16 bf16x2 __attribute__((ext_vector_type(2)));
typedef __bf16 bf16x4 __attribute__((ext_vector_type(4)));
typedef __bf16 bf16x8 __attribute__((ext_vector_type(8)));
typedef float f32x4 __attribute__((ext_vector_type(4)));
typedef float f32x16 __attribute__((ext_vector_type(16)));

#define MFMA16(a, b, c) __builtin_amdgcn_mfma_f32_16x16x32_bf16(a, b, c, 0, 0, 0)
#define MFMA32(a, b, c) __builtin_amdgcn_mfma_f32_32x32x16_bf16(a, b, c, 0, 0, 0)
#define QSCALE 0.1803368801111204f  // 0.125 * log2(e): folded into W's Q-columns

// async global->LDS, 16B/lane, dest = wave-uniform base + lane*16
__device__ __forceinline__ void gload_lds16(const __bf16* g, __bf16* l) {
  __builtin_amdgcn_global_load_lds((const __attribute__((address_space(1))) void*)g,
                                   (__attribute__((address_space(3))) void*)l,
                                   16, 0, 0);
}

// ---------------------------------------------------------------------------
// Kernel 0: convert X fp32 -> bf16
// ---------------------------------------------------------------------------
__global__ __launch_bounds__(256) void convert_x(const float* __restrict__ in,
                                                 __bf16* __restrict__ out) {
  int i = blockIdx.x * 256 + threadIdx.x;
  float4 v = ((const float4*)in)[i];
  bf16x4 o = {(__bf16)v.x, (__bf16)v.y, (__bf16)v.z, (__bf16)v.w};
  *(bf16x4*)&out[i * 4] = o;
}

// ---------------------------------------------------------------------------
// Kernel 1: transpose+convert W fp32 [1024,3072] -> Wt bf16 [3072,1024].
//   Q output-features (bx<16) pre-scaled by 0.125*log2(e).
// ---------------------------------------------------------------------------
__global__ __launch_bounds__(256) void transpose_w(const float* __restrict__ W,
                                                   __bf16* __restrict__ Wt) {
  __shared__ __bf16 tile[64][65];
  const int bx = blockIdx.x;
  const int by = blockIdx.y;
  const int t = threadIdx.x;
  const int lr = t >> 6;
  const int lc = t & 63;
  const float sc = (bx < 16) ? QSCALE : 1.0f;  // block-uniform
#pragma unroll
  for (int i = 0; i < 16; ++i) {
    int r = lr + i * 4;
    tile[r][lc] = (__bf16)(W[(size_t)(by * 64 + r) * 3072 + bx * 64 + lc] * sc);
  }
  __syncthreads();
#pragma unroll
  for (int i = 0; i < 16; ++i) {
    int r = lr + i * 4;
    Wt[(size_t)(bx * 64 + r) * 1024 + by * 64 + lc] = tile[lc][r];
  }
}

// ---------------------------------------------------------------------------
// Kernel 2: QKV = X @ W, deep-pipeline rewrite (T2+T3+T4+T5).
//   BM=256, BN=128, BK=64, 512 thr (8 waves, 4Mx2N, 64x64/wave).
//   Grid 24x32 = 768 = exactly 3 blocks/CU rounds.
//   2-slot LDS ring (96KB dynamic): iter c computes slot[c&1] while staging
//   K-tile c+1 into the OTHER slot (free since last barrier) -> no
//   read/write overlap ever. ONE raw barrier + one vmcnt(0)+lgkmcnt(0)
//   fence per K-tile; the 6 stage-issues go out in phases 0-1 so they get
//   ~3 compute-phases of latency cover before the drain (issue-early).
//   32 MFMA per barrier per wave (2x the old 2-barrier/BK=32 structure).
//   T2 swizzle: LDS col ^= row bits 2,3 (elem bits 4,5). global_load_lds
//   writes linearly, so the swizzle is applied by pre-swizzling the per-lane
//   GLOBAL source col (rule #21); ds_reads apply the same XOR. Round-trip:
//   LDS[r][c] holds G[r][c ^ swz(r)] -> read col = c ^ swz(r). Conflict
//   audit: frag-read start-bank = quad*8^(l16&12)<<2 spans all 8 groups ->
//   all 32 banks busy, minimum 8 lanes/group. Coalescing: XOR permutes
//   within a 128B line.
//   Epilogues unchanged: Q/K (n0<2048) -> QK row-major; V -> Vt fused
//   transpose.
// ---------------------------------------------------------------------------
#define GSLOT 24576  // elems per slot: A 256x64 = 16384 + B 128x64 = 8192

__global__ __launch_bounds__(512, 2) void gemm_qkv(const __bf16* __restrict__ X,
                                                   const __bf16* __restrict__ Wt,
                                                   __bf16* __restrict__ QK,
                                                   __bf16* __restrict__ Vt) {
  extern __shared__ __bf16 lds[];
  const int t = threadIdx.x;
  const int lane = t & 63;
  const int w = t >> 6;
  const int quad = lane >> 4;
  const int l16 = lane & 15;
  const int n0 = blockIdx.x * 128;
  const int m0 = blockIdx.y * 256;
  const int wm = (w >> 1) * 64;  // 4 M-waves
  const int wn = (w & 1) * 64;   // 2 N-waves
  // read swizzle: row bits 2,3 (= l16 bits 2,3) -> col-elem bits 4,5
  const int sw = (lane & 12) << 2;
  // stage source pre-swizzle: staged row = base8 + (lane>>3); row bit2 =
  // lane bit5, row bit3 = w bit0 (bases are w*8 + a*64)
  const int colSw = ((lane & 7) << 3) ^ ((lane & 32) >> 1) ^ ((w & 1) << 5);

  const __bf16* Asrc = &X[(size_t)(m0 + w * 8 + (lane >> 3)) * 1024 + colSw];
  const __bf16* Bsrc = &Wt[(size_t)(n0 + w * 8 + (lane >> 3)) * 1024 + colSw];
  const int dstAw = w * 8 * 64;          // wave's A staging base (elems)
  const int dstBw = 16384 + w * 8 * 64;  // wave's B staging base

  f32x4 acc[4][4] = {};

  // ---- prologue: stage K-tile 0 -> slot 0, drain, barrier ----
  {
    __bf16* T = lds;
#pragma unroll
    for (int a = 0; a < 4; ++a)
      gload_lds16(Asrc + (size_t)a * 64 * 1024, T + dstAw + a * 4096);
#pragma unroll
    for (int b = 0; b < 2; ++b)
      gload_lds16(Bsrc + (size_t)b * 64 * 1024, T + dstBw + b * 4096);
    asm volatile("s_waitcnt vmcnt(0)" ::: "memory");
    __builtin_amdgcn_sched_barrier(0);
    __builtin_amdgcn_s_barrier();
    __builtin_amdgcn_sched_barrier(0);
  }

  for (int c = 0; c < 16; ++c) {
    __bf16* S = lds + (c & 1) * GSLOT;          // compute slot (K-tile c)
    __bf16* T = lds + ((c & 1) ^ 1) * GSLOT;    // stage slot (K-tile c+1)
    const size_t kn = (size_t)(c + 1) * 64;
    const bool st = c < 15;

    // ---- phase 0: issue A stages a0-a2; read af01 + all bf; MFMA m01 x n01
    if (st) {
      gload_lds16(Asrc + kn, T + dstAw);
      gload_lds16(Asrc + (size_t)64 * 1024 + kn, T + dstAw + 4096);
      gload_lds16(Asrc + (size_t)128 * 1024 + kn, T + dstAw + 2 * 4096);
    }
    bf16x8 af0[2][2], af1[2][2], bf[4][2];
#pragma unroll
    for (int mi = 0; mi < 2; ++mi)
#pragma unroll
      for (int kk = 0; kk < 2; ++kk)
        af0[mi][kk] = *(const bf16x8*)&S[(wm + mi * 16 + l16) * 64 +
                                         ((kk * 32 + quad * 8) ^ sw)];
#pragma unroll
    for (int ni = 0; ni < 4; ++ni)
#pragma unroll
      for (int kk = 0; kk < 2; ++kk)
        bf[ni][kk] = *(const bf16x8*)&S[16384 + (wn + ni * 16 + l16) * 64 +
                                        ((kk * 32 + quad * 8) ^ sw)];
    __builtin_amdgcn_s_setprio(1);
#pragma unroll
    for (int mi = 0; mi < 2; ++mi)
#pragma unroll
      for (int ni = 0; ni < 2; ++ni)
#pragma unroll
        for (int kk = 0; kk < 2; ++kk)
          acc[mi][ni] = MFMA16(af0[mi][kk], bf[ni][kk], acc[mi][ni]);
    __builtin_amdgcn_s_setprio(0);

    // ---- phase 1: issue A a3 + B b0,b1; MFMA m01 x n23 ----
    if (st) {
      gload_lds16(Asrc + (size_t)192 * 1024 + kn, T + dstAw + 3 * 4096);
      gload_lds16(Bsrc + kn, T + dstBw);
      gload_lds16(Bsrc + (size_t)64 * 1024 + kn, T + dstBw + 4096);
    }
    __builtin_amdgcn_s_setprio(1);
#pragma unroll
    for (int mi = 0; mi < 2; ++mi)
#pragma unroll
      for (int ni = 0; ni < 2; ++ni)
#pragma unroll
        for (int kk = 0; kk < 2; ++kk)
          acc[mi][2 + ni] = MFMA16(af0[mi][kk], bf[2 + ni][kk], acc[mi][2 + ni]);
    __builtin_amdgcn_s_setprio(0);

    // ---- phase 2: read af23; MFMA m23 x n23 ----
#pragma unroll
    for (int mi = 0; mi < 2; ++mi)
#pragma unroll
      for (int kk = 0; kk < 2; ++kk)
        af1[mi][kk] = *(const bf16x8*)&S[(wm + (2 + mi) * 16 + l16) * 64 +
                                         ((kk * 32 + quad * 8) ^ sw)];
    __builtin_amdgcn_s_setprio(1);
#pragma unroll
    for (int mi = 0; mi < 2; ++mi)
#pragma unroll
      for (int ni = 0; ni < 2; ++ni)
#pragma unroll
        for (int kk = 0; kk < 2; ++kk)
          acc[2 + mi][2 + ni] = MFMA16(af1[mi][kk], bf[2 + ni][kk], acc[2 + mi][2 + ni]);
    __builtin_amdgcn_s_setprio(0);

    // ---- phase 3: MFMA m23 x n01 (reuse bf01) ----
    __builtin_amdgcn_s_setprio(1);
#pragma unroll
    for (int mi = 0; mi < 2; ++mi)
#pragma unroll
      for (int ni = 0; ni < 2; ++ni)
#pragma unroll
        for (int kk = 0; kk < 2; ++kk)
          acc[2 + mi][ni] = MFMA16(af1[mi][kk], bf[ni][kk], acc[2 + mi][ni]);
    __builtin_amdgcn_s_setprio(0);

    // ---- fence: my reads retired + next tile resident; one barrier ----
    asm volatile("s_waitcnt vmcnt(0) lgkmcnt(0)" ::: "memory");
    __builtin_amdgcn_sched_barrier(0);
    __builtin_amdgcn_s_barrier();
    __builtin_amdgcn_sched_barrier(0);
  }

  if (n0 < 2048) {
    // Q/K epilogue: row-major QK, stride 2048
#pragma unroll
    for (int mi = 0; mi < 4; ++mi)
#pragma unroll
      for (int ni = 0; ni < 4; ++ni)
#pragma unroll
        for (int r = 0; r < 4; ++r) {
          int row = m0 + wm + mi * 16 + quad * 4 + r;
          int col = n0 + wn + ni * 16 + l16;
          QK[(size_t)row * 2048 + col] = (__bf16)acc[mi][ni][r];
        }
  } else {
    // V epilogue: fused transpose into Vt[bh][d][key]; 4 consecutive keys
#pragma unroll
    for (int mi = 0; mi < 4; ++mi)
#pragma unroll
      for (int ni = 0; ni < 4; ++ni) {
        int v = n0 + wn + ni * 16 + l16 - 2048;
        int hh = v >> 6, d = v & 63;
        int row0 = m0 + wm + mi * 16 + quad * 4;
        int bb = row0 >> 11, key = row0 & 2047;
        bf16x4 pk = {(__bf16)acc[mi][ni][0], (__bf16)acc[mi][ni][1],
                     (__bf16)acc[mi][ni][2], (__bf16)acc[mi][ni][3]};
        *(bf16x4*)&Vt[((size_t)(bb * 16 + hh) * 64 + d) * 2048 + key] = pk;
      }
  }
}

// ---------------------------------------------------------------------------
// Kernel 3: flash attention, 32x32x16 MFMA, PERMUTED-K staging + T1 remap.
//   Verified R8: 87.7 us, FETCH 24.6 MB, 0 bank conflicts. Unchanged.
// ---------------------------------------------------------------------------
#define AT_LD 72  // 144B rows, 16B-aligned

__global__ __launch_bounds__(256) void attn(const __bf16* __restrict__ QK,
                                            const __bf16* __restrict__ Vt,
                                            float* __restrict__ Out) {
  const int t = threadIdx.x;
  const int lane = t & 63;
  const int wave = t >> 6;
  const int l31 = lane & 31;
  const int half = lane >> 5;

  // ---- XCD-aware remap (T1) ----
  const int flat = blockIdx.x + (blockIdx.y << 4) + (blockIdx.z << 8);
  const int xcd = flat & 7;
  const int idx = flat >> 3;
  const int bh = xcd * 8 + (idx >> 4);  // 8 (b,h) panels per XCD
  const int qb = idx & 15;
  const int b = bh >> 4;
  const int h = bh & 15;
  const int q0w = qb * 128 + wave * 32;

  const size_t base = (size_t)b * 2048 * 2048;
  const __bf16* Qb = QK + base + h * 64;
  const __bf16* Kb = QK + base + 1024 + h * 64;
  const __bf16* Vtb = Vt + (size_t)(b * 16 + h) * 64 * 2048;  // [d][key]

  __shared__ __bf16 Ks[64 * AT_LD];  // [perm(key)][d]
  __shared__ __bf16 Vs[64 * AT_LD];  // [d][key]

  // Q as B-operand: lane holds Q[q0w+l31][dc*16 + half*8 + j]  (pre-scaled)
  bf16x8 qf[4];
#pragma unroll
  for (int dc = 0; dc < 4; ++dc)
    qf[dc] = *(const bf16x8*)&Qb[(size_t)(q0w + l31) * 2048 + dc * 16 + half * 8];

  f32x16 o[2] = {};
  float lsum = 0.0f;

  const int srow = t >> 2;      // staging row 0..63
  const int sc = (t & 3) * 16;  // staging col chunk
  // K dest row: swap bits 2<->3 (involution); bits 0,1,4,5 kept
  const int prow = (srow & 51) | ((srow & 4) << 1) | ((srow & 8) >> 1);

  for (int kv0 = 0; kv0 < 2048; kv0 += 64) {
    // ---- stage K (row-permuted) and V ----
    bf16x8 k0v = *(const bf16x8*)&Kb[(size_t)(kv0 + srow) * 2048 + sc];
    bf16x8 k1v = *(const bf16x8*)&Kb[(size_t)(kv0 + srow) * 2048 + sc + 8];
    bf16x8 v0v = *(const bf16x8*)&Vtb[(size_t)srow * 2048 + kv0 + sc];
    bf16x8 v1v = *(const bf16x8*)&Vtb[(size_t)srow * 2048 + kv0 + sc + 8];
    __syncthreads();
    *(bf16x8*)&Ks[prow * AT_LD + sc] = k0v;
    *(bf16x8*)&Ks[prow * AT_LD + sc + 8] = k1v;
    *(bf16x8*)&Vs[srow * AT_LD + sc] = v0v;
    *(bf16x8*)&Vs[srow * AT_LD + sc + 8] = v1v;
    __syncthreads();

    // ---- S^T = K.Q^T per 32-row tile; exp2 directly into A-frag order ----
    bf16x8 pf[4];
#pragma unroll
    for (int kt = 0; kt < 2; ++kt) {
      f32x16 c = {};
#pragma unroll
      for (int dc = 0; dc < 4; ++dc) {
        bf16x8 kf = *(const bf16x8*)&Ks[(kt * 32 + l31) * AT_LD + dc * 16 + half * 8];
        c = MFMA32(kf, qf[dc], c);
      }
#pragma unroll
      for (int kkl = 0; kkl < 2; ++kkl) {
        bf16x8 f;
#pragma unroll
        for (int j = 0; j < 8; ++j) {
          float e = __builtin_amdgcn_exp2f(c[8 * kkl + 4 * (j >> 2) + (j & 3)]);
          lsum += e;
          f[j] = (__bf16)e;
        }
        pf[kt * 2 + kkl] = f;
      }
    }

    // ---- O += P V ----
#pragma unroll
    for (int dt = 0; dt < 2; ++dt)
#pragma unroll
      for (int kk = 0; kk < 4; ++kk) {
        bf16x8 vf = *(const bf16x8*)&Vs[(dt * 32 + l31) * AT_LD + kk * 16 + half * 8];
        o[dt] = MFMA32(pf[kk], vf, o[dt]);
      }
  }

  // ---- denominator: the two halves partition each q's keys ----
  lsum += __shfl_xor(lsum, 32);
  float inv = 1.0f / lsum;  // valid for q == l31

  float iv[16];
#pragma unroll
  for (int r = 0; r < 16; ++r)
    iv[r] = __shfl(inv, (r & 3) + 8 * (r >> 2) + 4 * half);

  // ---- epilogue: O C-layout col=l31=d(+32dt), row=q regmap ----
#pragma unroll
  for (int dt = 0; dt < 2; ++dt)
#pragma unroll
    for (int r = 0; r < 16; ++r) {
      int qr = (r & 3) + 8 * (r >> 2) + 4 * half;
      Out[(size_t)(b * 2048 + q0w + qr) * 1024 + h * 64 + dt * 32 + l31] =
          o[dt][r] * iv[r];
    }
}

// ---------------------------------------------------------------------------
extern "C" void kernel_launch(void* const* d_in, const int* in_sizes, int n_in,
                              void* d_out, int out_size, void* d_ws, size_t ws_size,
                              hipStream_t stream) {
  const float* x = (const float*)d_in[0];        // [4,2048,1024] fp32
  const float* w = (const float*)d_in[1];        // [1024,3072]  fp32
  float* out = (float*)d_out;                    // [4,2048,1024] fp32

  __bf16* Wt = (__bf16*)d_ws;                    // [3072,1024]   6.29 MB
  __bf16* QK = Wt + (size_t)3072 * 1024;         // [8192,2048]  33.55 MB
  __bf16* Xb = QK + (size_t)8192 * 2048;         // [8192,1024]  16.78 MB
  __bf16* Vtr = Xb + (size_t)8192 * 1024;        // [64,64,2048] 16.78 MB

  // one-time: allow 96KB dynamic LDS for gemm_qkv (harmless if redundant)
  static bool attr_done = false;
  if (!attr_done) {
    (void)hipFuncSetAttribute((const void*)gemm_qkv,
                              hipFuncAttributeMaxDynamicSharedMemorySize,
                              2 * GSLOT * (int)sizeof(__bf16));
    attr_done = true;
  }

  convert_x<<<8192, 256, 0, stream>>>(x, Xb);
  transpose_w<<<dim3(48, 16), 256, 0, stream>>>(w, Wt);
  gemm_qkv<<<dim3(24, 32), 512, 2 * GSLOT * sizeof(__bf16), stream>>>(Xb, Wt, QK, Vtr);
  attn<<<dim3(16, 16, 4), 256, 0, stream>>>(QK, Vtr, out);
}